// Round 12
// baseline (23.515 us; speedup 1.0000x reference)
//
#include <hip/hip_runtime.h>
#include <math.h>

#define EPS 1e-6f
#define FLT_BIG 3.402823466e+38f

constexpr int BLK = 256;   // threads per block
constexpr int MB  = 32;    // m's per block
constexpr int MPT = 8;     // m's per thread
constexpr int NG  = 4;     // m-groups per block (MB/MPT)
constexpr int NSL = 64;    // l-slices per block (BLK/NG)
constexpr int L1C = 4096;  // L1 (compile-time for LDS sizing)

// Zero out[0..B-1]; stream-ordered before k_all's atomicAdds.
__global__ void k_zero(float* __restrict__ out, int B) {
    if (threadIdx.x < B) out[threadIdx.x] = 0.0f;
}

// One block = (m-block of 32 m's, b). Stages ALL of c1[b] in LDS once, then
// each thread: 8 m's x 64 strided l's of min(||p||^2 - 2 p.q), +||q||^2,
// 64-thread min-reduce per m (shfl_xor + LDS), sqrt, fixed-tree sum over the
// block's 32 m's, one atomicAdd(out[b]) per block. No part[] intermediate.
__global__ void __launch_bounds__(BLK, 2)
k_all(const float* __restrict__ c1, const float* __restrict__ c2,
      const float* __restrict__ res, float* __restrict__ out,
      int L1, int L2) {
    __shared__ float4 tile[L1C];       // 64 KiB
    __shared__ float wred[4 * MB];     // 4 waves x 32 m's

    const int blk = blockIdx.x;        // 0..127
    const int b   = blockIdx.y;
    const int tid = threadIdx.x;
    const int g   = tid & (NG - 1);    // m-group 0..3
    const int sl  = tid >> 2;          // l-slice 0..63

    // Stage c1[b] as (||p||^2, -2x, -2y, -2z); i = k*BLK+tid -> conflict-free.
    const float* src = c1 + (size_t)b * L1 * 3;
    #pragma unroll
    for (int k = 0; k < L1C / BLK; ++k) {
        const int i = k * BLK + tid;
        float x = src[3 * i], y = src[3 * i + 1], z = src[3 * i + 2];
        tile[i] = make_float4(fmaf(x, x, fmaf(y, y, z * z)),
                              -2.0f * x, -2.0f * y, -2.0f * z);
    }

    // 8 consecutive q's (24 consecutive floats) while staging is in flight.
    const int m0 = blk * MB + g * MPT;
    const float* q = c2 + ((size_t)b * L2 + m0) * 3;
    float q0[MPT], q1[MPT], q2[MPT], qq[MPT], mn[MPT];
    #pragma unroll
    for (int j = 0; j < MPT; ++j) {
        q0[j] = q[3 * j] - EPS; q1[j] = q[3 * j + 1] - EPS; q2[j] = q[3 * j + 2] - EPS;
        qq[j] = fmaf(q0[j], q0[j], fmaf(q1[j], q1[j], q2[j] * q2[j]));
        mn[j] = FLT_BIG;
    }
    __syncthreads();

    // 64 l's strided by NSL: l = k*64 + sl. 2 l's per iter (min3 fusion);
    // one broadcast ds_read_b128 feeds 8 m's.
    #pragma unroll 4
    for (int k = 0; k < NSL; k += 2) {
        float4 pa = tile[k * NSL + sl];
        float4 pb = tile[(k + 1) * NSL + sl];
        #pragma unroll
        for (int j = 0; j < MPT; ++j) {
            float ta = fmaf(pa.w, q2[j], fmaf(pa.z, q1[j], fmaf(pa.y, q0[j], pa.x)));
            float tb = fmaf(pb.w, q2[j], fmaf(pb.z, q1[j], fmaf(pb.y, q0[j], pb.x)));
            mn[j] = fminf(mn[j], fminf(ta, tb));
        }
    }

    // Per-m reduce across the 16 l-slices in this wave (lanes stride 4).
    const int wv = tid >> 6;
    #pragma unroll
    for (int j = 0; j < MPT; ++j) {
        float v = mn[j] + qq[j];       // min commutes with +const
        v = fminf(v, __shfl_xor(v, 4, 64));
        v = fminf(v, __shfl_xor(v, 8, 64));
        v = fminf(v, __shfl_xor(v, 16, 64));
        v = fminf(v, __shfl_xor(v, 32, 64));
        if ((tid & 63) < NG)           // lane == g
            wred[wv * MB + g * MPT + j] = v;
    }
    __syncthreads();

    // First 32 threads: min across 4 waves, sqrt, fixed-tree sum, one atomic.
    if (tid < MB) {
        float v = fminf(fminf(wred[tid], wred[MB + tid]),
                        fminf(wred[2 * MB + tid], wred[3 * MB + tid]));
        float d = sqrtf(fmaxf(v, 0.0f));
        d += __shfl_down(d, 16, 64);
        d += __shfl_down(d, 8, 64);
        d += __shfl_down(d, 4, 64);
        d += __shfl_down(d, 2, 64);
        d += __shfl_down(d, 1, 64);
        if (tid == 0) atomicAdd(&out[b], d * res[0] / (float)L2);
    }
}

extern "C" void kernel_launch(void* const* d_in, const int* in_sizes, int n_in,
                              void* d_out, int out_size, void* d_ws, size_t ws_size,
                              hipStream_t stream) {
    const float* c1  = (const float*)d_in[0];
    const float* c2  = (const float*)d_in[1];
    const float* res = (const float*)d_in[2];
    float* out = (float*)d_out;

    const int B = out_size;                 // 4
    const int D = 3;
    const int L1 = in_sizes[0] / (B * D);   // 4096
    const int L2 = in_sizes[1] / (B * D);   // 4096

    k_zero<<<1, 64, 0, stream>>>(out, B);

    dim3 grid(L2 / MB, B);                  // 128 x 4 = 512 blocks
    k_all<<<grid, BLK, 0, stream>>>(c1, c2, res, out, L1, L2);
}

// Round 13
// 21.743 us; speedup vs baseline: 1.0815x; 1.0815x over previous
//
#include <hip/hip_runtime.h>
#include <math.h>

#define EPS 1e-6f
#define FLT_BIG 3.402823466e+38f

constexpr int BLK = 256;     // threads per block
constexpr int MPT = 8;       // m's per thread (amortize LDS broadcast over 8 m's)
constexpr int NCHUNK = 64;   // l-chunks (grid.y) -> 512 blocks = 2 waves/SIMD
constexpr int NMB = 2;       // m-blocks (grid.x): NMB*BLK*MPT = 4096 = L2
constexpr int CLK = 64;      // l's per chunk (L1 / NCHUNK)
constexpr int TMB = 32;      // k_tail: m's per block
constexpr int TCG = 8;       // k_tail: chunk-groups (threads per m)

// Dispatch 1. Grid (NMB, NCHUNK, B) = 512 blocks, 256 threads.
// Per (b,chunk): stage CLK points of c1 as (||p||^2,-2x,-2y,-2z) in LDS; each
// thread computes chunk-partial min_l(||p||^2 - 2 p.q) + ||q||^2 for 8 m's
// (q = c2[m] - eps, wave-uniform broadcast tile reads) and stores to
// part[b][chunk][m]. Plain stores, no atomics, no fences.
// Block (0,0,b) thread 0 also zeroes out[b] (stream-ordered before k_tail).
__global__ void __launch_bounds__(BLK)
k_min(const float* __restrict__ c1, const float* __restrict__ c2,
      float* __restrict__ part, float* __restrict__ out, int L1, int L2) {
    __shared__ float4 tile[CLK];

    const int mb = blockIdx.x, chunk = blockIdx.y, b = blockIdx.z;
    const int tid = threadIdx.x;

    if (mb == 0 && chunk == 0 && tid == 0) out[b] = 0.0f;

    const int l0 = chunk * CLK;
    const float* src = c1 + ((size_t)b * L1 + l0) * 3;
    if (tid < CLK) {
        float x = src[3 * tid], y = src[3 * tid + 1], z = src[3 * tid + 2];
        tile[tid] = make_float4(fmaf(x, x, fmaf(y, y, z * z)),
                                -2.0f * x, -2.0f * y, -2.0f * z);
    }
    __syncthreads();

    const int mbase = mb * (BLK * MPT) + tid;

    float q0[MPT], q1[MPT], q2[MPT], mn[MPT];
    #pragma unroll
    for (int j = 0; j < MPT; ++j) {
        const float* q = c2 + ((size_t)b * L2 + mbase + j * BLK) * 3;
        q0[j] = q[0] - EPS; q1[j] = q[1] - EPS; q2[j] = q[2] - EPS;
        mn[j] = FLT_BIG;
    }

    // 2 l's per iteration; one broadcast ds_read_b128 feeds 8 m's.
    #pragma unroll 2
    for (int l = 0; l < CLK; l += 2) {
        float4 pa = tile[l], pb = tile[l + 1];
        #pragma unroll
        for (int j = 0; j < MPT; ++j) {
            float ta = fmaf(pa.w, q2[j], fmaf(pa.z, q1[j], fmaf(pa.y, q0[j], pa.x)));
            float tb = fmaf(pb.w, q2[j], fmaf(pb.z, q1[j], fmaf(pb.y, q0[j], pb.x)));
            mn[j] = fminf(mn[j], fminf(ta, tb));
        }
    }

    float* dst = part + ((size_t)b * NCHUNK + chunk) * L2;
    #pragma unroll
    for (int j = 0; j < MPT; ++j) {
        const float qq = fmaf(q0[j], q0[j], fmaf(q1[j], q1[j], q2[j] * q2[j]));
        dst[mbase + j * BLK] = mn[j] + qq;
    }
}

// Dispatch 2. Grid (L2/TMB, B) = 512 blocks, 256 threads. Each block owns 32
// m's; threads split 8-ways over the 64 chunks (8 independent coalesced loads
// each), LDS [8][32] min-combine, sqrt + fixed-tree sum in wave 0, one
// atomicAdd(out[b]) per block.
__global__ void __launch_bounds__(BLK)
k_tail(const float* __restrict__ part, const float* __restrict__ res,
       float* __restrict__ out, int L2) {
    const int b = blockIdx.y;
    const int ml = threadIdx.x & (TMB - 1);          // m within block
    const int cg = threadIdx.x >> 5;                 // chunk-group 0..7
    const int m = blockIdx.x * TMB + ml;

    float v = FLT_BIG;
    #pragma unroll
    for (int c = cg * (NCHUNK / TCG); c < (cg + 1) * (NCHUNK / TCG); ++c)
        v = fminf(v, part[((size_t)b * NCHUNK + c) * L2 + m]);

    __shared__ float red[TCG][TMB];
    red[cg][ml] = v;
    __syncthreads();

    if (threadIdx.x < TMB) {
        float vv = red[0][ml];
        #pragma unroll
        for (int g = 1; g < TCG; ++g) vv = fminf(vv, red[g][ml]);
        float d = sqrtf(fmaxf(vv, 0.0f));
        d += __shfl_down(d, 16, 64);
        d += __shfl_down(d, 8, 64);
        d += __shfl_down(d, 4, 64);
        d += __shfl_down(d, 2, 64);
        d += __shfl_down(d, 1, 64);
        if (threadIdx.x == 0) atomicAdd(&out[b], d * res[0] / (float)L2);
    }
}

extern "C" void kernel_launch(void* const* d_in, const int* in_sizes, int n_in,
                              void* d_out, int out_size, void* d_ws, size_t ws_size,
                              hipStream_t stream) {
    const float* c1  = (const float*)d_in[0];
    const float* c2  = (const float*)d_in[1];
    const float* res = (const float*)d_in[2];
    float* out = (float*)d_out;

    const int B = out_size;                 // 4
    const int D = 3;
    const int L1 = in_sizes[0] / (B * D);   // 4096
    const int L2 = in_sizes[1] / (B * D);   // 4096

    float* part = (float*)d_ws;             // B*NCHUNK*L2 floats (4 MiB)

    dim3 g1(NMB, NCHUNK, B);                // 512 blocks
    k_min<<<g1, BLK, 0, stream>>>(c1, c2, part, out, L1, L2);

    dim3 g2(L2 / TMB, B);                   // 512 blocks
    k_tail<<<g2, BLK, 0, stream>>>(part, res, out, L2);
}

// Round 14
// 20.659 us; speedup vs baseline: 1.1382x; 1.0525x over previous
//
#include <hip/hip_runtime.h>
#include <math.h>

#define EPS 1e-6f
#define FLT_BIG 3.402823466e+38f

typedef __attribute__((ext_vector_type(2))) float f32x2;

constexpr int BLK = 256;     // threads per block
constexpr int MPT = 8;       // m's per thread (amortize LDS broadcast over 8 m's)
constexpr int NCHUNK = 64;   // l-chunks (grid.y) -> 512 blocks = 2 waves/SIMD
constexpr int NMB = 2;       // m-blocks (grid.x): NMB*BLK*MPT = 4096 = L2
constexpr int CLK = 64;      // l's per chunk (L1 / NCHUNK)
constexpr int NPAIR = CLK / 2;

// Dispatch 1. Grid (NMB, NCHUNK, B) = 512 blocks, 256 threads.
// Paired-SoA LDS tile: per l-pair p, [n0 n1 | x0 x1 | y0 y1 | z0 z1] where
// n=||p||^2, (x,y,z) scaled by -2. Inner loop: wave-uniform ds_read_b64
// broadcasts + v_pk_fma_f32 (2 l's per instruction) + v_min3_f32.
// Each thread: chunk-partial min over 64 l's for 8 m's -> part[b][chunk][m].
// Block (0,0,b) thread 0 zeroes out[b] (stream-ordered before k_tail).
__global__ void __launch_bounds__(BLK)
k_min(const float* __restrict__ c1, const float* __restrict__ c2,
      float* __restrict__ part, float* __restrict__ out, int L1, int L2) {
    __shared__ float tileF[NPAIR * 8];   // 1 KiB

    const int mb = blockIdx.x, chunk = blockIdx.y, b = blockIdx.z;
    const int tid = threadIdx.x;

    if (mb == 0 && chunk == 0 && tid == 0) out[b] = 0.0f;

    const int l0 = chunk * CLK;
    const float* src = c1 + ((size_t)b * L1 + l0) * 3;
    if (tid < CLK) {
        float x = src[3 * tid], y = src[3 * tid + 1], z = src[3 * tid + 2];
        const int p = tid >> 1, h = tid & 1;
        float* base = &tileF[p * 8 + h];
        base[0] = fmaf(x, x, fmaf(y, y, z * z));
        base[2] = -2.0f * x;
        base[4] = -2.0f * y;
        base[6] = -2.0f * z;
    }
    __syncthreads();

    const int mbase = mb * (BLK * MPT) + tid;

    f32x2 q0[MPT], q1[MPT], q2[MPT];
    float qq[MPT], mn[MPT];
    #pragma unroll
    for (int j = 0; j < MPT; ++j) {
        const float* q = c2 + ((size_t)b * L2 + mbase + j * BLK) * 3;
        const float a = q[0] - EPS, bb = q[1] - EPS, c = q[2] - EPS;
        q0[j] = (f32x2){a, a};
        q1[j] = (f32x2){bb, bb};
        q2[j] = (f32x2){c, c};
        qq[j] = fmaf(a, a, fmaf(bb, bb, c * c));
        mn[j] = FLT_BIG;
    }

    #pragma unroll 4
    for (int p = 0; p < NPAIR; ++p) {
        const f32x2 np = *(const f32x2*)&tileF[p * 8 + 0];
        const f32x2 xp = *(const f32x2*)&tileF[p * 8 + 2];
        const f32x2 yp = *(const f32x2*)&tileF[p * 8 + 4];
        const f32x2 zp = *(const f32x2*)&tileF[p * 8 + 6];
        #pragma unroll
        for (int j = 0; j < MPT; ++j) {
            f32x2 t0, t1, t2;
            asm("v_pk_fma_f32 %0, %1, %2, %3"
                : "=v"(t0) : "v"(xp), "v"(q0[j]), "v"(np));
            asm("v_pk_fma_f32 %0, %1, %2, %3"
                : "=v"(t1) : "v"(yp), "v"(q1[j]), "v"(t0));
            asm("v_pk_fma_f32 %0, %1, %2, %3"
                : "=v"(t2) : "v"(zp), "v"(q2[j]), "v"(t1));
            mn[j] = fminf(mn[j], fminf(t2.x, t2.y));   // -> v_min3_f32
        }
    }

    float* dst = part + ((size_t)b * NCHUNK + chunk) * L2;
    #pragma unroll
    for (int j = 0; j < MPT; ++j)
        dst[mbase + j * BLK] = mn[j] + qq[j];
}

// Dispatch 2 (round-11 version, best measured). Grid (L2/BLK, B) = 64 blocks;
// thread owns one m: min over 64 chunks, sqrt, fixed-order wave reduce, one
// atomicAdd per block.
__global__ void __launch_bounds__(BLK)
k_tail(const float* __restrict__ part, const float* __restrict__ res,
       float* __restrict__ out, int L2) {
    const int b = blockIdx.y;
    const int m = blockIdx.x * BLK + threadIdx.x;

    float v = FLT_BIG;
    #pragma unroll 8
    for (int c = 0; c < NCHUNK; ++c)
        v = fminf(v, part[((size_t)b * NCHUNK + c) * L2 + m]);
    float sum = sqrtf(fmaxf(v, 0.0f));

    #pragma unroll
    for (int s = 32; s > 0; s >>= 1)
        sum += __shfl_down(sum, s, 64);

    __shared__ float wred[BLK / 64];
    const int wid = threadIdx.x >> 6;
    if ((threadIdx.x & 63) == 0) wred[wid] = sum;
    __syncthreads();

    if (threadIdx.x == 0) {
        float tot = 0.0f;
        #pragma unroll
        for (int w = 0; w < BLK / 64; ++w) tot += wred[w];
        atomicAdd(&out[b], tot * res[0] / (float)L2);
    }
}

extern "C" void kernel_launch(void* const* d_in, const int* in_sizes, int n_in,
                              void* d_out, int out_size, void* d_ws, size_t ws_size,
                              hipStream_t stream) {
    const float* c1  = (const float*)d_in[0];
    const float* c2  = (const float*)d_in[1];
    const float* res = (const float*)d_in[2];
    float* out = (float*)d_out;

    const int B = out_size;                 // 4
    const int D = 3;
    const int L1 = in_sizes[0] / (B * D);   // 4096
    const int L2 = in_sizes[1] / (B * D);   // 4096

    float* part = (float*)d_ws;             // B*NCHUNK*L2 floats (4 MiB)

    dim3 g1(NMB, NCHUNK, B);                // 512 blocks
    k_min<<<g1, BLK, 0, stream>>>(c1, c2, part, out, L1, L2);

    dim3 g2(L2 / BLK, B);                   // 64 blocks
    k_tail<<<g2, BLK, 0, stream>>>(part, res, out, L2);
}

// Round 15
// 18.560 us; speedup vs baseline: 1.2669x; 1.1131x over previous
//
#include <hip/hip_runtime.h>
#include <math.h>

#define EPS 1e-6f
#define FLT_BIG 3.402823466e+38f

constexpr int BLK = 256;     // threads per block
constexpr int MPT = 8;       // m's per thread (amortize LDS broadcast over 8 m's)
constexpr int NCHUNK = 64;   // l-chunks (grid.y) -> 512 blocks = 2 waves/SIMD
constexpr int NMB = 2;       // m-blocks (grid.x): NMB*BLK*MPT = 4096 = L2
constexpr int CLK = 64;      // l's per chunk (L1 / NCHUNK)

// Dispatch 1. Grid (NMB, NCHUNK, B) = 512 blocks, 256 threads.
// Per (b,chunk): stage CLK points of c1 as (||p||^2,-2x,-2y,-2z) in LDS; each
// thread computes chunk-partial min_l(||p||^2 - 2 p.q) + ||q||^2 for 8 m's
// (q = c2[m] - eps) and stores to part[b][chunk][m]. Plain stores, no atomics.
// Block (0,0,b) thread 0 also zeroes out[b] (stream-ordered before k_tail).
__global__ void __launch_bounds__(BLK)
k_min(const float* __restrict__ c1, const float* __restrict__ c2,
      float* __restrict__ part, float* __restrict__ out, int L1, int L2) {
    __shared__ float4 tile[CLK];

    const int mb = blockIdx.x, chunk = blockIdx.y, b = blockIdx.z;
    const int tid = threadIdx.x;

    if (mb == 0 && chunk == 0 && tid == 0) out[b] = 0.0f;

    const int l0 = chunk * CLK;
    const float* src = c1 + ((size_t)b * L1 + l0) * 3;
    if (tid < CLK) {
        float x = src[3 * tid], y = src[3 * tid + 1], z = src[3 * tid + 2];
        tile[tid] = make_float4(fmaf(x, x, fmaf(y, y, z * z)),
                                -2.0f * x, -2.0f * y, -2.0f * z);
    }
    __syncthreads();

    const int mbase = mb * (BLK * MPT) + tid;

    float q0[MPT], q1[MPT], q2[MPT], mn[MPT];
    #pragma unroll
    for (int j = 0; j < MPT; ++j) {
        const float* q = c2 + ((size_t)b * L2 + mbase + j * BLK) * 3;
        q0[j] = q[0] - EPS; q1[j] = q[1] - EPS; q2[j] = q[2] - EPS;
        mn[j] = FLT_BIG;
    }

    // 2 l's per iteration; one broadcast ds_read_b128 feeds 8 m's.
    #pragma unroll 2
    for (int l = 0; l < CLK; l += 2) {
        float4 pa = tile[l], pb = tile[l + 1];
        #pragma unroll
        for (int j = 0; j < MPT; ++j) {
            float ta = fmaf(pa.w, q2[j], fmaf(pa.z, q1[j], fmaf(pa.y, q0[j], pa.x)));
            float tb = fmaf(pb.w, q2[j], fmaf(pb.z, q1[j], fmaf(pb.y, q0[j], pb.x)));
            mn[j] = fminf(mn[j], fminf(ta, tb));
        }
    }

    float* dst = part + ((size_t)b * NCHUNK + chunk) * L2;
    #pragma unroll
    for (int j = 0; j < MPT; ++j) {
        const float qq = fmaf(q0[j], q0[j], fmaf(q1[j], q1[j], q2[j] * q2[j]));
        dst[mbase + j * BLK] = mn[j] + qq;
    }
}

// Dispatch 2. Grid (L2/BLK, B) = 64 blocks, 256 threads; thread owns one m:
// min over 64 chunks, sqrt, fixed-order block reduce, one atomicAdd per block.
__global__ void __launch_bounds__(BLK)
k_tail(const float* __restrict__ part, const float* __restrict__ res,
       float* __restrict__ out, int L2) {
    const int b = blockIdx.y;
    const int m = blockIdx.x * BLK + threadIdx.x;

    float v = FLT_BIG;
    #pragma unroll 8
    for (int c = 0; c < NCHUNK; ++c)
        v = fminf(v, part[((size_t)b * NCHUNK + c) * L2 + m]);
    float sum = sqrtf(fmaxf(v, 0.0f));

    // Wave shuffle reduce (fixed order), then LDS across 4 waves.
    #pragma unroll
    for (int s = 32; s > 0; s >>= 1)
        sum += __shfl_down(sum, s, 64);

    __shared__ float wred[BLK / 64];
    const int wid = threadIdx.x >> 6;
    if ((threadIdx.x & 63) == 0) wred[wid] = sum;
    __syncthreads();

    if (threadIdx.x == 0) {
        float tot = 0.0f;
        #pragma unroll
        for (int w = 0; w < BLK / 64; ++w) tot += wred[w];
        atomicAdd(&out[b], tot * res[0] / (float)L2);
    }
}

extern "C" void kernel_launch(void* const* d_in, const int* in_sizes, int n_in,
                              void* d_out, int out_size, void* d_ws, size_t ws_size,
                              hipStream_t stream) {
    const float* c1  = (const float*)d_in[0];
    const float* c2  = (const float*)d_in[1];
    const float* res = (const float*)d_in[2];
    float* out = (float*)d_out;

    const int B = out_size;                 // 4
    const int D = 3;
    const int L1 = in_sizes[0] / (B * D);   // 4096
    const int L2 = in_sizes[1] / (B * D);   // 4096

    float* part = (float*)d_ws;             // B*NCHUNK*L2 floats (4 MiB)

    dim3 g1(NMB, NCHUNK, B);                // 512 blocks
    k_min<<<g1, BLK, 0, stream>>>(c1, c2, part, out, L1, L2);

    dim3 g2(L2 / BLK, B);                   // 64 blocks
    k_tail<<<g2, BLK, 0, stream>>>(part, res, out, L2);
}